// Round 5
// baseline (3510.828 us; speedup 1.0000x reference)
//
#include <hip/hip_runtime.h>
#include <math.h>

#define B_  50
#define T_  512
#define I_  1024
#define H_  512
#define NG_ 2048
#define NBLK 256  // 8 groups x 32 blocks, 1 block/CU
#define FLS  32   // flag stride in ints (128 B per flag line)

typedef __attribute__((ext_vector_type(8))) short short8;   // 8 bf16 (4 VGPRs)
typedef __attribute__((ext_vector_type(4))) float f32x4;    // MFMA accumulator
typedef unsigned short ushort_t;
typedef unsigned long long ull_t;

__device__ __forceinline__ float sigmf(float x) {
    return 1.0f / (1.0f + __expf(-x));
}
// overflow-safe tanh via e^{-2|x|} in (0,1]
__device__ __forceinline__ float tanh_fast(float x) {
    float ax = fabsf(x);
    float e  = __expf(-2.0f * ax);
    float t  = (1.0f - e) / (1.0f + e);
    return copysignf(t, x);
}
__device__ __forceinline__ ushort_t bf16_rne(float x) {
    unsigned u = __float_as_uint(x);
    unsigned r = u + 0x7fffu + ((u >> 16) & 1u);
    return (ushort_t)(r >> 16);
}
__device__ __forceinline__ float bf16_tof(ushort_t h) {
    return __uint_as_float(((unsigned)h) << 16);
}

// ---------------------------------------------------------------------------
// MFMA split-bf16 GEMM: C[m][n] = bias[n] + sum_k A[m][k] * W[n][k].
// 128x128 tile, BK=32, 4 waves x (4x4 16x16x32 tiles), 3 products per tile
// (AhiBhi + AloBhi + AhiBlo) for ~fp32 accuracy. LDS frag arrays padded to
// stride 40 ushorts (80 B) -> conflict-free ds_read_b128.
// tmode=1: store row m to ((m % T)*B + m/T)  (xg -> [T][B][NG] layout).
// ---------------------------------------------------------------------------
__global__ __launch_bounds__(256) void gemm_bias_mfma(
    const float* __restrict__ A, const float* __restrict__ W,
    const float* __restrict__ bias, float* __restrict__ C,
    int M, int N, int K, int tmode) {
    __shared__ ushort_t Ah[128 * 40];
    __shared__ ushort_t Al[128 * 40];
    __shared__ ushort_t Wh[128 * 40];
    __shared__ ushort_t Wl[128 * 40];
    const int tid = threadIdx.x;
    const int m0 = blockIdx.y * 128, n0 = blockIdx.x * 128;
    const int w = tid >> 6, L = tid & 63;
    const int wm = (w & 1) * 64, wn = (w >> 1) * 64;
    const int rr = tid >> 1, kh = (tid & 1) << 4;

    f32x4 acc[4][4];
#pragma unroll
    for (int i = 0; i < 4; ++i)
#pragma unroll
        for (int j = 0; j < 4; ++j) acc[i][j] = (f32x4){0.f, 0.f, 0.f, 0.f};

    for (int k0 = 0; k0 < K; k0 += 32) {
        float4 av[4], wv[4];
        const float* ap = A + (size_t)(m0 + rr) * K + k0 + kh;
        const float* wp = W + (size_t)(n0 + rr) * K + k0 + kh;
#pragma unroll
        for (int e = 0; e < 4; ++e) {
            av[e] = *(const float4*)(ap + 4 * e);
            wv[e] = *(const float4*)(wp + 4 * e);
        }
        __syncthreads();   // previous iter's frag reads complete
        union { ushort_t s[16]; ull_t u[4]; } ha, la, hw, lw;
#pragma unroll
        for (int e = 0; e < 4; ++e) {
            float as[4] = {av[e].x, av[e].y, av[e].z, av[e].w};
            float ws[4] = {wv[e].x, wv[e].y, wv[e].z, wv[e].w};
#pragma unroll
            for (int f = 0; f < 4; ++f) {
                ushort_t hi = bf16_rne(as[f]);
                ha.s[e * 4 + f] = hi;
                la.s[e * 4 + f] = bf16_rne(as[f] - bf16_tof(hi));
                hi = bf16_rne(ws[f]);
                hw.s[e * 4 + f] = hi;
                lw.s[e * 4 + f] = bf16_rne(ws[f] - bf16_tof(hi));
            }
        }
        {
            ull_t* d0 = (ull_t*)&Ah[rr * 40 + kh];
            ull_t* d1 = (ull_t*)&Al[rr * 40 + kh];
            ull_t* d2 = (ull_t*)&Wh[rr * 40 + kh];
            ull_t* d3 = (ull_t*)&Wl[rr * 40 + kh];
#pragma unroll
            for (int e = 0; e < 4; ++e) {
                d0[e] = ha.u[e]; d1[e] = la.u[e];
                d2[e] = hw.u[e]; d3[e] = lw.u[e];
            }
        }
        __syncthreads();
        const int ko = (L >> 4) * 8;
        short8 ahf[4], alf[4], whf[4], wlf[4];
#pragma unroll
        for (int i = 0; i < 4; ++i) {
            ahf[i] = *(const short8*)&Ah[(wm + i * 16 + (L & 15)) * 40 + ko];
            alf[i] = *(const short8*)&Al[(wm + i * 16 + (L & 15)) * 40 + ko];
            whf[i] = *(const short8*)&Wh[(wn + i * 16 + (L & 15)) * 40 + ko];
            wlf[i] = *(const short8*)&Wl[(wn + i * 16 + (L & 15)) * 40 + ko];
        }
#pragma unroll
        for (int i = 0; i < 4; ++i)
#pragma unroll
            for (int j = 0; j < 4; ++j) {
                acc[i][j] = __builtin_amdgcn_mfma_f32_16x16x32_bf16(ahf[i], whf[j], acc[i][j], 0, 0, 0);
                acc[i][j] = __builtin_amdgcn_mfma_f32_16x16x32_bf16(alf[i], whf[j], acc[i][j], 0, 0, 0);
                acc[i][j] = __builtin_amdgcn_mfma_f32_16x16x32_bf16(ahf[i], wlf[j], acc[i][j], 0, 0, 0);
            }
    }

    // epilogue: D[row=(L>>4)*4+r][col=L&15] per tile
#pragma unroll
    for (int j = 0; j < 4; ++j) {
        int col = n0 + wn + j * 16 + (L & 15);
        float bv = bias[col];
#pragma unroll
        for (int i = 0; i < 4; ++i) {
#pragma unroll
            for (int r = 0; r < 4; ++r) {
                int row = m0 + wm + i * 16 + (L >> 4) * 4 + r;
                size_t crow = tmode ? ((size_t)(row & (T_ - 1)) * B_ + (row >> 9))
                                    : (size_t)row;
                C[crow * N + col] = acc[i][j][r] + bv;
            }
        }
    }
}

// ---------------------------------------------------------------------------
// Build compressed A-fragment buffer from an h state (one block per group).
// Layout per group (8192 ushorts): [hl(2)][ks(16)][cl(32)][jj(8)],
// cl = m' + 8*oct, element = h[bat0+m'][ks*32 + oct*8 + jj] as bf16 hi/lo.
// ---------------------------------------------------------------------------
__global__ __launch_bounds__(256) void init_hfrag(
    const float* __restrict__ h0, ushort_t* __restrict__ hf) {
    const int g = blockIdx.x, tid = threadIdx.x;
    const int bat0 = (g < 2) ? 7 * g : 14 + 6 * (g - 2);
    const int cnt  = (g < 2) ? 7 : 6;
    ushort_t* og = hf + (size_t)g * 8192;
    for (int i = tid; i < 8192; i += 256) {
        int jj = i & 7, cl = (i >> 3) & 31, ks = (i >> 8) & 15, hl = i >> 12;
        int m = cl & 7, oct = cl >> 3;
        int j = ks * 32 + oct * 8 + jj;
        float x = 0.0f;
        if (m < cnt) x = h0[(size_t)(bat0 + m) * H_ + j];
        ushort_t hi = bf16_rne(x);
        og[i] = hl ? bf16_rne(x - bf16_tof(hi)) : hi;
    }
}

// ---------------------------------------------------------------------------
// Fused 2-layer persistent LSTM scan, software-pipelined (structure = R2:
// per-wave poll/stage, no stage barrier).
//
// R5 deltas vs R2 (both compile-safe, no new sync semantics):
//  1. W_ih1-lo B-frags moved LDS -> registers (Bih1l[4][4]; unified VGPR/AGPR
//     file has headroom at 1 wave/SIMD). Removes 16 ds_read_b128/step/wave
//     and frees 64 KB LDS.
//  2. d0/d1 partial buffers double-buffered by step parity; end-of-step
//     barrier C DELETED -> 1 barrier/step. Waves 2/3 flow straight from
//     MFMA(s) into poll/stage(s+1), overlapping the whole gate phase.
//
// Safety without C: distance-1 d reuse covered by parity buffers. Distance-2
// (MFMA(s+2) writes d[p] while gates(s) reads d[p]) covered transitively:
// poll(s+2) needs producers' flags >= s+2 -> their B(s+1) -> their polls
// (s+1) over all 32 group blocks -> our flag(s+1), which was stored after
// our gates(s) d-reads fed the vmcnt-drained publishes. Anti-overwrite of
// the h exchange buffers: unchanged R2 argument (flag=s stored after B(s-1),
// whose implicit per-wave vmcnt(0) drained all stage(s-1) reads).
// ---------------------------------------------------------------------------
__global__ __launch_bounds__(256, 1) void lstm_fused(
    const float* __restrict__ xg,     // [T][B][NG] layer0 gates, bias included
    ushort_t* __restrict__ hf0A, ushort_t* __restrict__ hf0B,
    ushort_t* __restrict__ hf1A, ushort_t* __restrict__ hf1B,
    const float* __restrict__ c0,     // [2][B][H]
    const float* __restrict__ W_hh0,  // [NG][H]
    const float* __restrict__ W_hh1,  // [NG][H]
    const float* __restrict__ W_ih1,  // [NG][H]
    const float* __restrict__ b1,     // [NG]
    float* __restrict__ hplain,       // [B][H] final layer-1 h
    int* __restrict__ flags) {        // NBLK*FLS ints, zeroed
    __shared__ __align__(16) ushort_t hfL0[16384];   // 32 KB expanded h0 A-frags
    __shared__ __align__(16) ushort_t hfL1[16384];   // 32 KB expanded h1 A-frags
    __shared__ float d0b[2][4 * 4 * 8 * 16];         // 2x8 KB layer0 partials
    __shared__ float d1b[2][4 * 4 * 8 * 16];         // 2x8 KB layer1 partials
    const int tid = threadIdx.x, bid = blockIdx.x;
    const int g = bid >> 5, mB = bid & 31;
    const int j0 = mB * 16;
    const int bat0 = (g < 2) ? 7 * g : 14 + 6 * (g - 2);
    const int cnt  = (g < 2) ? 7 : 6;
    const int w = tid >> 6, L = tid & 63;

    // zero pad lanes (el&15 >= 8) of both frag buffers; stage never writes
    // them, MFMA reads them as 0.
    {
        ull_t* u0 = (ull_t*)hfL0;
        ull_t* u1 = (ull_t*)hfL1;
        for (int i = tid; i < 4096; i += 256)
            if ((((i >> 1) & 63) & 15) >= 8) { u0[i] = 0ULL; u1[i] = 0ULL; }
    }

    // ---- one-time W preload (all six B-frag arrays in regs/AGPRs) ----
    short8 Bhh0h[4][4], Bhh0l[4][4], Bhh1h[4][4], Bhh1l[4][4];
    short8 Bih1h[4][4], Bih1l[4][4];
    {
        const int n = L & 15, oct = L >> 4;
#pragma unroll
        for (int q = 0; q < 4; ++q) {
            const size_t row = (size_t)(q * H_ + j0 + n) * H_;
#pragma unroll
            for (int kk = 0; kk < 4; ++kk) {
                int kbase = (w * 4 + kk) * 32 + oct * 8;
                // W_hh0
                {
                    float4 f0 = *(const float4*)(W_hh0 + row + kbase);
                    float4 f1 = *(const float4*)(W_hh0 + row + kbase + 4);
                    float xs[8] = {f0.x, f0.y, f0.z, f0.w, f1.x, f1.y, f1.z, f1.w};
                    union { ushort_t s[8]; short8 v; } uh, ul;
#pragma unroll
                    for (int e = 0; e < 8; ++e) {
                        ushort_t hi = bf16_rne(xs[e]);
                        uh.s[e] = hi; ul.s[e] = bf16_rne(xs[e] - bf16_tof(hi));
                    }
                    Bhh0h[q][kk] = uh.v; Bhh0l[q][kk] = ul.v;
                }
                // W_hh1
                {
                    float4 f0 = *(const float4*)(W_hh1 + row + kbase);
                    float4 f1 = *(const float4*)(W_hh1 + row + kbase + 4);
                    float xs[8] = {f0.x, f0.y, f0.z, f0.w, f1.x, f1.y, f1.z, f1.w};
                    union { ushort_t s[8]; short8 v; } uh, ul;
#pragma unroll
                    for (int e = 0; e < 8; ++e) {
                        ushort_t hi = bf16_rne(xs[e]);
                        uh.s[e] = hi; ul.s[e] = bf16_rne(xs[e] - bf16_tof(hi));
                    }
                    Bhh1h[q][kk] = uh.v; Bhh1l[q][kk] = ul.v;
                }
                // W_ih1: hi and lo both in regs
                {
                    float4 f0 = *(const float4*)(W_ih1 + row + kbase);
                    float4 f1 = *(const float4*)(W_ih1 + row + kbase + 4);
                    float xs[8] = {f0.x, f0.y, f0.z, f0.w, f1.x, f1.y, f1.z, f1.w};
                    union { ushort_t s[8]; short8 v; } uh, ul;
#pragma unroll
                    for (int e = 0; e < 8; ++e) {
                        ushort_t hi = bf16_rne(xs[e]);
                        uh.s[e] = hi; ul.s[e] = bf16_rne(xs[e] - bf16_tof(hi));
                    }
                    Bih1h[q][kk] = uh.v;
                    Bih1l[q][kk] = ul.v;
                }
            }
        }
    }

    // ---- gate-phase identities ----
    const int gm0 = tid >> 3, jlp0 = (tid & 7) * 2;
    const bool gok0 = (tid < 56) && (gm0 < cnt);
    const int gb0 = (bat0 + gm0 < B_) ? bat0 + gm0 : B_ - 1;
    float c0a = 0.f, c0b = 0.f;
    if (gok0) {
        c0a = c0[(size_t)gb0 * H_ + j0 + jlp0];
        c0b = c0[(size_t)gb0 * H_ + j0 + jlp0 + 1];
    }
    float2 xr[4];
    if (tid < 56) {
#pragma unroll
        for (int q = 0; q < 4; ++q)
            xr[q] = *(const float2*)(xg + (size_t)gb0 * NG_ + q * H_ + j0 + jlp0);
    }
    const int u1 = tid - 64;
    const int gm1 = u1 >> 3, jlp1 = (u1 & 7) * 2;
    const bool gok1 = (tid >= 64) && (tid < 120) && (gm1 < cnt);
    const int gb1 = (gok1 && bat0 + gm1 < B_) ? bat0 + gm1 : B_ - 1;
    float c1a = 0.f, c1b = 0.f;
    float2 b1r[4];
    if (gok1) {
        c1a = c0[(size_t)(B_ + gb1) * H_ + j0 + jlp1];
        c1b = c0[(size_t)(B_ + gb1) * H_ + j0 + jlp1 + 1];
#pragma unroll
        for (int q = 0; q < 4; ++q)
            b1r[q] = *(const float2*)(b1 + q * H_ + j0 + jlp1);
    }

    __syncthreads();   // pad-zero visible

    const short8* ap0 = (const short8*)hfL0;
    const short8* ap1 = (const short8*)hfL1;
    const f32x4 vzero = {0.f, 0.f, 0.f, 0.f};

    // poll pointer: this wave's 16 flags (8 producers x 2), 4x redundant
    const int l4 = L & 15;
    const int* pollp = flags + (size_t)(g * 32 + 8 * w + (l4 & 7)) * FLS + (l4 >> 3);

    for (int s = 0; s <= T_; ++s) {
        const ushort_t* r0 = (s & 1) ? hf0A : hf0B;   // h0(s-1)
        ushort_t*       w0 = (s & 1) ? hf0B : hf0A;
        const ushort_t* r1 = (s & 1) ? hf1B : hf1A;   // h1(s-2)
        ushort_t*       w1 = (s & 1) ? hf1A : hf1B;
        float* dw0 = d0b[s & 1];
        float* dw1 = d1b[s & 1];

        // ---- per-wave poll: wait for this wave's 8 producer blocks ----
        {
            for (;;) {
                int fv = __hip_atomic_load(pollp, __ATOMIC_RELAXED,
                                           __HIP_MEMORY_SCOPE_AGENT);
                if (__all(fv >= s)) break;
                __builtin_amdgcn_s_sleep(2);
            }
        }

        // ---- per-wave stage: this wave's ks slice of both frag sets ----
        {
            const ull_t* s0 = (const ull_t*)(r0 + (size_t)g * 8192);
            const ull_t* s1 = (const ull_t*)(r1 + (size_t)g * 8192);
            ull_t* l0 = (ull_t*)hfL0;
            ull_t* l1 = (ull_t*)hfL1;
            ull_t v0[8], v1[8];
#pragma unroll
            for (int hl = 0; hl < 2; ++hl)
#pragma unroll
                for (int i = 0; i < 4; ++i) {
                    int u = hl * 1024 + w * 256 + i * 64 + L;
                    v0[hl * 4 + i] = __hip_atomic_load(s0 + u, __ATOMIC_RELAXED,
                                                       __HIP_MEMORY_SCOPE_AGENT);
                    v1[hl * 4 + i] = __hip_atomic_load(s1 + u, __ATOMIC_RELAXED,
                                                       __HIP_MEMORY_SCOPE_AGENT);
                }
#pragma unroll
            for (int hl = 0; hl < 2; ++hl)
#pragma unroll
                for (int i = 0; i < 4; ++i) {
                    int u = hl * 1024 + w * 256 + i * 64 + L;
                    int jjh = u & 1, cl = (u >> 1) & 31, ks = (u >> 6) & 15;
                    int el = (cl & 7) + 16 * (cl >> 3);
                    int di = ((hl * 16 + ks) * 64 + el) * 2 + jjh;
                    l0[di] = v0[hl * 4 + i];
                    l1[di] = v1[hl * 4 + i];
                }
        }
        // no barrier: each wave's MFMA reads only lines it staged itself.

        // ---- layer-0 MFMA (t0 = s) ----
        if (s < T_) {
            f32x4 acc[4];
#pragma unroll
            for (int q = 0; q < 4; ++q) acc[q] = vzero;
#pragma unroll
            for (int kk = 0; kk < 4; ++kk) {
                int ksp = w * 4 + kk;
                short8 Ahi = ap0[ksp * 64 + L];
                short8 Alo = ap0[1024 + ksp * 64 + L];
#pragma unroll
                for (int q = 0; q < 4; ++q) {
                    acc[q] = __builtin_amdgcn_mfma_f32_16x16x32_bf16(Ahi, Bhh0h[q][kk], acc[q], 0, 0, 0);
                    acc[q] = __builtin_amdgcn_mfma_f32_16x16x32_bf16(Alo, Bhh0h[q][kk], acc[q], 0, 0, 0);
                    acc[q] = __builtin_amdgcn_mfma_f32_16x16x32_bf16(Ahi, Bhh0l[q][kk], acc[q], 0, 0, 0);
                }
            }
#pragma unroll
            for (int q = 0; q < 4; ++q)
#pragma unroll
                for (int r = 0; r < 4; ++r) {
                    int m = (L >> 4) * 4 + r;
                    if (m < 8) dw0[((w * 4 + q) * 8 + m) * 16 + (L & 15)] = acc[q][r];
                }
        }
        // ---- layer-1 MFMA (t1 = s-1): W_ih1@h0(s-1) + W_hh1@h1(s-2) ----
        if (s >= 1) {
            f32x4 acc[4];
#pragma unroll
            for (int q = 0; q < 4; ++q) acc[q] = vzero;
#pragma unroll
            for (int kk = 0; kk < 4; ++kk) {
                int ksp = w * 4 + kk;
                short8 A0h = ap0[ksp * 64 + L];
                short8 A0l = ap0[1024 + ksp * 64 + L];
                short8 A1h = ap1[ksp * 64 + L];
                short8 A1l = ap1[1024 + ksp * 64 + L];
#pragma unroll
                for (int q = 0; q < 4; ++q) {
                    acc[q] = __builtin_amdgcn_mfma_f32_16x16x32_bf16(A0h, Bih1h[q][kk], acc[q], 0, 0, 0);
                    acc[q] = __builtin_amdgcn_mfma_f32_16x16x32_bf16(A0l, Bih1h[q][kk], acc[q], 0, 0, 0);
                    acc[q] = __builtin_amdgcn_mfma_f32_16x16x32_bf16(A0h, Bih1l[q][kk], acc[q], 0, 0, 0);
                    acc[q] = __builtin_amdgcn_mfma_f32_16x16x32_bf16(A1h, Bhh1h[q][kk], acc[q], 0, 0, 0);
                    acc[q] = __builtin_amdgcn_mfma_f32_16x16x32_bf16(A1l, Bhh1h[q][kk], acc[q], 0, 0, 0);
                    acc[q] = __builtin_amdgcn_mfma_f32_16x16x32_bf16(A1h, Bhh1l[q][kk], acc[q], 0, 0, 0);
                }
            }
#pragma unroll
            for (int q = 0; q < 4; ++q)
#pragma unroll
                for (int r = 0; r < 4; ++r) {
                    int m = (L >> 4) * 4 + r;
                    if (m < 8) dw1[((w * 4 + q) * 8 + m) * 16 + (L & 15)] = acc[q][r];
                }
        }
        __syncthreads();   // B: d partials complete; drains stage loads

        // ---- layer-0 gate phase (wave 0) + flagA ----
        if (s < T_) {
            if (gok0) {
                float ga[4], gb[4];
#pragma unroll
                for (int q = 0; q < 4; ++q) {
                    float sx = 0.f, sy = 0.f;
#pragma unroll
                    for (int ww = 0; ww < 4; ++ww) {
                        const float2 p = *(const float2*)&dw0[((ww * 4 + q) * 8 + gm0) * 16 + jlp0];
                        sx += p.x; sy += p.y;
                    }
                    ga[q] = sx + xr[q].x;
                    gb[q] = sy + xr[q].y;
                }
                float cna = sigmf(ga[1]) * c0a + sigmf(ga[0]) * tanh_fast(ga[2]);
                float hna = sigmf(ga[3]) * tanh_fast(cna);
                float cnb = sigmf(gb[1]) * c0b + sigmf(gb[0]) * tanh_fast(gb[2]);
                float hnb = sigmf(gb[3]) * tanh_fast(cnb);
                c0a = cna; c0b = cnb;
                ushort_t hia = bf16_rne(hna), hib = bf16_rne(hnb);
                ushort_t loa = bf16_rne(hna - bf16_tof(hia));
                ushort_t lob = bf16_rne(hnb - bf16_tof(hib));
                int jA = j0 + jlp0;
                int cl = gm0 + 8 * ((jA >> 3) & 3);
                int ks = jA >> 5, jj = jA & 7;
                ushort_t* og = w0 + (size_t)g * 8192;
                unsigned hv = (unsigned)hia | ((unsigned)hib << 16);
                unsigned lv = (unsigned)loa | ((unsigned)lob << 16);
                __hip_atomic_store((unsigned*)(og + (ks * 256 + cl * 8 + jj)), hv,
                                   __ATOMIC_RELAXED, __HIP_MEMORY_SCOPE_AGENT);
                __hip_atomic_store((unsigned*)(og + (4096 + ks * 256 + cl * 8 + jj)), lv,
                                   __ATOMIC_RELAXED, __HIP_MEMORY_SCOPE_AGENT);
            }
        }
        if (tid == 0) {
            asm volatile("s_waitcnt vmcnt(0)" ::: "memory");
            __hip_atomic_store(flags + (size_t)bid * FLS + 0, s + 1,
                               __ATOMIC_RELAXED, __HIP_MEMORY_SCOPE_AGENT);
        }
        // prefetch next xg tile (after flagA so it doesn't delay the signal)
        if (tid < 56 && s + 1 < T_) {
#pragma unroll
            for (int q = 0; q < 4; ++q)
                xr[q] = *(const float2*)(xg + ((size_t)(s + 1) * B_ + gb0) * NG_ + q * H_ + j0 + jlp0);
        }

        // ---- layer-1 gate phase (wave 1) + flagB ----
        if (s >= 1 && gok1) {
            float ga[4], gb[4];
#pragma unroll
            for (int q = 0; q < 4; ++q) {
                float sx = 0.f, sy = 0.f;
#pragma unroll
                for (int ww = 0; ww < 4; ++ww) {
                    const float2 p = *(const float2*)&dw1[((ww * 4 + q) * 8 + gm1) * 16 + jlp1];
                    sx += p.x; sy += p.y;
                }
                ga[q] = sx + b1r[q].x;
                gb[q] = sy + b1r[q].y;
            }
            float cna = sigmf(ga[1]) * c1a + sigmf(ga[0]) * tanh_fast(ga[2]);
            float hna = sigmf(ga[3]) * tanh_fast(cna);
            float cnb = sigmf(gb[1]) * c1b + sigmf(gb[0]) * tanh_fast(gb[2]);
            float hnb = sigmf(gb[3]) * tanh_fast(cnb);
            c1a = cna; c1b = cnb;
            ushort_t hia = bf16_rne(hna), hib = bf16_rne(hnb);
            ushort_t loa = bf16_rne(hna - bf16_tof(hia));
            ushort_t lob = bf16_rne(hnb - bf16_tof(hib));
            int jA = j0 + jlp1;
            int cl = gm1 + 8 * ((jA >> 3) & 3);
            int ks = jA >> 5, jj = jA & 7;
            ushort_t* og = w1 + (size_t)g * 8192;
            unsigned hv = (unsigned)hia | ((unsigned)hib << 16);
            unsigned lv = (unsigned)loa | ((unsigned)lob << 16);
            __hip_atomic_store((unsigned*)(og + (ks * 256 + cl * 8 + jj)), hv,
                               __ATOMIC_RELAXED, __HIP_MEMORY_SCOPE_AGENT);
            __hip_atomic_store((unsigned*)(og + (4096 + ks * 256 + cl * 8 + jj)), lv,
                               __ATOMIC_RELAXED, __HIP_MEMORY_SCOPE_AGENT);
            if (s == T_) *(float2*)(hplain + (size_t)gb1 * H_ + jA) = make_float2(hna, hnb);
        }
        if (tid == 64) {
            asm volatile("s_waitcnt vmcnt(0)" ::: "memory");
            __hip_atomic_store(flags + (size_t)bid * FLS + 1, s + 1,
                               __ATOMIC_RELAXED, __HIP_MEMORY_SCOPE_AGENT);
        }
        // no barrier C: d buffers parity-swap; distance-2 reuse is protected
        // by the cross-block flag chain (see header comment).
    }
}

// ---------------------------------------------------------------------------
// head: hT layout [b][H]
// ---------------------------------------------------------------------------
__global__ __launch_bounds__(512) void head(
    const float* __restrict__ hT, const float* __restrict__ lin1_W,
    const float* __restrict__ lin1_b, const float* __restrict__ lin2_W,
    const float* __restrict__ lin2_b, float* __restrict__ out) {
    __shared__ float zs[B_][10];
    int tid = threadIdx.x;
    if (tid < B_ * 10) {
        int b = tid / 10, u = tid % 10;
        float acc = lin1_b[u];
        for (int j = 0; j < H_; j += 4) {
            float4 hv = *(const float4*)&hT[(size_t)b * H_ + j];
            float4 wv = *(const float4*)&lin1_W[(size_t)u * H_ + j];
            acc = fmaf(hv.x, wv.x, acc);
            acc = fmaf(hv.y, wv.y, acc);
            acc = fmaf(hv.z, wv.z, acc);
            acc = fmaf(hv.w, wv.w, acc);
        }
        zs[b][u] = tanh_fast(acc);
    }
    __syncthreads();
    if (tid < B_ * 2) {
        int b = tid >> 1, o = tid & 1;
        float acc = lin2_b[o];
#pragma unroll
        for (int u = 0; u < 10; ++u)
            acc = fmaf(zs[b][u], lin2_W[o * 10 + u], acc);
        out[b * 2 + o] = acc;
    }
}

// ---------------------------------------------------------------------------
extern "C" void kernel_launch(void* const* d_in, const int* in_sizes, int n_in,
                              void* d_out, int out_size, void* d_ws, size_t ws_size,
                              hipStream_t stream) {
    const float* input  = (const float*)d_in[0];
    const float* pca_W  = (const float*)d_in[1];
    const float* pca_b  = (const float*)d_in[2];
    const float* W_ih0  = (const float*)d_in[3];
    const float* W_hh0  = (const float*)d_in[4];
    const float* b0     = (const float*)d_in[5];
    const float* W_ih1  = (const float*)d_in[6];
    const float* W_hh1  = (const float*)d_in[7];
    const float* b1     = (const float*)d_in[8];
    const float* h0     = (const float*)d_in[9];
    const float* c0     = (const float*)d_in[10];
    const float* lin1_W = (const float*)d_in[11];
    const float* lin1_b = (const float*)d_in[12];
    const float* lin2_W = (const float*)d_in[13];
    const float* lin2_b = (const float*)d_in[14];
    float* out = (float*)d_out;

    float* ws = (float*)d_ws;
    size_t off = 0;
    float* xg     = ws + off; off += (size_t)B_ * T_ * NG_;  // [T][B][NG]
    float* xbuf   = ws + off; off += (size_t)B_ * T_ * H_;
    float* hplain = ws + off; off += B_ * H_;
    ushort_t* hf0A = (ushort_t*)(ws + off); off += 32768;    // 8 x 8192 ushorts
    ushort_t* hf0B = (ushort_t*)(ws + off); off += 32768;
    ushort_t* hf1A = (ushort_t*)(ws + off); off += 32768;
    ushort_t* hf1B = (ushort_t*)(ws + off); off += 32768;
    int* flg = (int*)(ws + off); off += NBLK * FLS;

    const int M = B_ * T_;  // 25600

    // flags must start at 0 (ws re-poisoned 0xAA before every timed launch)
    hipMemsetAsync(flg, 0, NBLK * FLS * sizeof(int), stream);

    // initial states -> frag buffers (read at s=0 / s=1 respectively)
    init_hfrag<<<8, 256, 0, stream>>>(h0, hf0B);
    init_hfrag<<<8, 256, 0, stream>>>(h0 + B_ * H_, hf1B);

    // 1. pca: xbuf = input @ pca_W^T + pca_b   (row-major [B*T][H])
    {
        dim3 g(H_ / 128, M / 128);
        gemm_bias_mfma<<<g, 256, 0, stream>>>(input, pca_W, pca_b, xbuf, M, H_, I_, 0);
    }
    // 2. xg0 = xbuf @ W_ih0^T + b0, stored [T][B][NG]
    {
        dim3 g(NG_ / 128, M / 128);
        gemm_bias_mfma<<<g, 256, 0, stream>>>(xbuf, W_ih0, b0, xg, M, NG_, H_, 1);
    }
    // 3. fused 2-layer pipelined scan (1 barrier/step, W_ih1 fully in regs)
    lstm_fused<<<NBLK, 256, 0, stream>>>(xg, hf0A, hf0B, hf1A, hf1B, c0,
                                         W_hh0, W_hh1, W_ih1, b1, hplain, flg);
    // 4. head
    head<<<1, 512, 0, stream>>>(hplain, lin1_W, lin1_b, lin2_W, lin2_b, out);
}

// Round 6
// 3307.678 us; speedup vs baseline: 1.0614x; 1.0614x over previous
//
#include <hip/hip_runtime.h>
#include <math.h>

#define B_  50
#define T_  512
#define I_  1024
#define H_  512
#define NG_ 2048
#define NBLK 256  // 8 groups x 32 blocks, 1 block/CU
#define FLS  32   // flag stride in ints (128 B per flag line)

typedef __attribute__((ext_vector_type(8))) short short8;   // 8 bf16 (4 VGPRs)
typedef __attribute__((ext_vector_type(4))) float f32x4;    // MFMA accumulator
typedef unsigned short ushort_t;
typedef unsigned long long ull_t;

__device__ __forceinline__ float sigmf(float x) {
    return 1.0f / (1.0f + __expf(-x));
}
// overflow-safe tanh via e^{-2|x|} in (0,1]
__device__ __forceinline__ float tanh_fast(float x) {
    float ax = fabsf(x);
    float e  = __expf(-2.0f * ax);
    float t  = (1.0f - e) / (1.0f + e);
    return copysignf(t, x);
}
__device__ __forceinline__ ushort_t bf16_rne(float x) {
    unsigned u = __float_as_uint(x);
    unsigned r = u + 0x7fffu + ((u >> 16) & 1u);
    return (ushort_t)(r >> 16);
}
__device__ __forceinline__ float bf16_tof(ushort_t h) {
    return __uint_as_float(((unsigned)h) << 16);
}

// ---------------------------------------------------------------------------
// MFMA split-bf16 GEMM: C[m][n] = bias[n] + sum_k A[m][k] * W[n][k].
// 128x128 tile, BK=32, 4 waves x (4x4 16x16x32 tiles), 3 products per tile
// (AhiBhi + AloBhi + AhiBlo) for ~fp32 accuracy. LDS frag arrays padded to
// stride 40 ushorts (80 B) -> conflict-free ds_read_b128.
// tmode=1: store row m to ((m % T)*B + m/T)  (xg -> [T][B][NG] layout).
// ---------------------------------------------------------------------------
__global__ __launch_bounds__(256) void gemm_bias_mfma(
    const float* __restrict__ A, const float* __restrict__ W,
    const float* __restrict__ bias, float* __restrict__ C,
    int M, int N, int K, int tmode) {
    __shared__ ushort_t Ah[128 * 40];
    __shared__ ushort_t Al[128 * 40];
    __shared__ ushort_t Wh[128 * 40];
    __shared__ ushort_t Wl[128 * 40];
    const int tid = threadIdx.x;
    const int m0 = blockIdx.y * 128, n0 = blockIdx.x * 128;
    const int w = tid >> 6, L = tid & 63;
    const int wm = (w & 1) * 64, wn = (w >> 1) * 64;
    const int rr = tid >> 1, kh = (tid & 1) << 4;

    f32x4 acc[4][4];
#pragma unroll
    for (int i = 0; i < 4; ++i)
#pragma unroll
        for (int j = 0; j < 4; ++j) acc[i][j] = (f32x4){0.f, 0.f, 0.f, 0.f};

    for (int k0 = 0; k0 < K; k0 += 32) {
        float4 av[4], wv[4];
        const float* ap = A + (size_t)(m0 + rr) * K + k0 + kh;
        const float* wp = W + (size_t)(n0 + rr) * K + k0 + kh;
#pragma unroll
        for (int e = 0; e < 4; ++e) {
            av[e] = *(const float4*)(ap + 4 * e);
            wv[e] = *(const float4*)(wp + 4 * e);
        }
        __syncthreads();   // previous iter's frag reads complete
        union { ushort_t s[16]; ull_t u[4]; } ha, la, hw, lw;
#pragma unroll
        for (int e = 0; e < 4; ++e) {
            float as[4] = {av[e].x, av[e].y, av[e].z, av[e].w};
            float ws[4] = {wv[e].x, wv[e].y, wv[e].z, wv[e].w};
#pragma unroll
            for (int f = 0; f < 4; ++f) {
                ushort_t hi = bf16_rne(as[f]);
                ha.s[e * 4 + f] = hi;
                la.s[e * 4 + f] = bf16_rne(as[f] - bf16_tof(hi));
                hi = bf16_rne(ws[f]);
                hw.s[e * 4 + f] = hi;
                lw.s[e * 4 + f] = bf16_rne(ws[f] - bf16_tof(hi));
            }
        }
        {
            ull_t* d0 = (ull_t*)&Ah[rr * 40 + kh];
            ull_t* d1 = (ull_t*)&Al[rr * 40 + kh];
            ull_t* d2 = (ull_t*)&Wh[rr * 40 + kh];
            ull_t* d3 = (ull_t*)&Wl[rr * 40 + kh];
#pragma unroll
            for (int e = 0; e < 4; ++e) {
                d0[e] = ha.u[e]; d1[e] = la.u[e];
                d2[e] = hw.u[e]; d3[e] = lw.u[e];
            }
        }
        __syncthreads();
        const int ko = (L >> 4) * 8;
        short8 ahf[4], alf[4], whf[4], wlf[4];
#pragma unroll
        for (int i = 0; i < 4; ++i) {
            ahf[i] = *(const short8*)&Ah[(wm + i * 16 + (L & 15)) * 40 + ko];
            alf[i] = *(const short8*)&Al[(wm + i * 16 + (L & 15)) * 40 + ko];
            whf[i] = *(const short8*)&Wh[(wn + i * 16 + (L & 15)) * 40 + ko];
            wlf[i] = *(const short8*)&Wl[(wn + i * 16 + (L & 15)) * 40 + ko];
        }
#pragma unroll
        for (int i = 0; i < 4; ++i)
#pragma unroll
            for (int j = 0; j < 4; ++j) {
                acc[i][j] = __builtin_amdgcn_mfma_f32_16x16x32_bf16(ahf[i], whf[j], acc[i][j], 0, 0, 0);
                acc[i][j] = __builtin_amdgcn_mfma_f32_16x16x32_bf16(alf[i], whf[j], acc[i][j], 0, 0, 0);
                acc[i][j] = __builtin_amdgcn_mfma_f32_16x16x32_bf16(ahf[i], wlf[j], acc[i][j], 0, 0, 0);
            }
    }

    // epilogue: D[row=(L>>4)*4+r][col=L&15] per tile
#pragma unroll
    for (int j = 0; j < 4; ++j) {
        int col = n0 + wn + j * 16 + (L & 15);
        float bv = bias[col];
#pragma unroll
        for (int i = 0; i < 4; ++i) {
#pragma unroll
            for (int r = 0; r < 4; ++r) {
                int row = m0 + wm + i * 16 + (L >> 4) * 4 + r;
                size_t crow = tmode ? ((size_t)(row & (T_ - 1)) * B_ + (row >> 9))
                                    : (size_t)row;
                C[crow * N + col] = acc[i][j][r] + bv;
            }
        }
    }
}

// ---------------------------------------------------------------------------
// Build compressed A-fragment buffer from an h state (one block per group).
// Layout per group (8192 ushorts): [hl(2)][ks(16)][cl(32)][jj(8)],
// cl = m' + 8*oct, element = h[bat0+m'][ks*32 + oct*8 + jj] as bf16 hi/lo.
// ---------------------------------------------------------------------------
__global__ __launch_bounds__(256) void init_hfrag(
    const float* __restrict__ h0, ushort_t* __restrict__ hf) {
    const int g = blockIdx.x, tid = threadIdx.x;
    const int bat0 = (g < 2) ? 7 * g : 14 + 6 * (g - 2);
    const int cnt  = (g < 2) ? 7 : 6;
    ushort_t* og = hf + (size_t)g * 8192;
    for (int i = tid; i < 8192; i += 256) {
        int jj = i & 7, cl = (i >> 3) & 31, ks = (i >> 8) & 15, hl = i >> 12;
        int m = cl & 7, oct = cl >> 3;
        int j = ks * 32 + oct * 8 + jj;
        float x = 0.0f;
        if (m < cnt) x = h0[(size_t)(bat0 + m) * H_ + j];
        ushort_t hi = bf16_rne(x);
        og[i] = hl ? bf16_rne(x - bf16_tof(hi)) : hi;
    }
}

// ---------------------------------------------------------------------------
// Fused 2-layer persistent LSTM scan (structure = R2: per-wave poll/stage,
// no stage barrier, W_ih1-lo in LDS wlo, 4 other W arrays in regs).
//
// R6 delta vs R2 (single change): d0/d1 partial buffers DOUBLE-BUFFERED by
// step parity; end-of-step barrier C DELETED -> 1 barrier/step. Waves flow
// from flag-publish(s) straight into poll/stage(s+1), overlapping the gate
// phase tail (gates + publish drain + flag detect) with next-step staging.
// LDS = 64K(hfL) + 32K(d dbuf) + 64K(wlo) = 163840 B = the full 160 KiB.
//
// Safety without C: distance-1 d reuse covered by parity buffers. Distance-2
// (MFMA(s+2) writes d[p] vs gates(s) reads d[p]) covered transitively:
// poll(s+2) needs producers' flags >= s+2 -> their B(s+1) -> their polls
// (s+1) over all 32 group blocks -> our flag(s+1), which was stored after
// our gates(s) d-reads fed the vmcnt-drained publishes. h-exchange
// anti-overwrite: unchanged R2 argument (flag=s stored after B(s-1), whose
// implicit per-wave vmcnt(0) drained all stage(s-1) reads).
// ---------------------------------------------------------------------------
__global__ __launch_bounds__(256, 1) void lstm_fused(
    const float* __restrict__ xg,     // [T][B][NG] layer0 gates, bias included
    ushort_t* __restrict__ hf0A, ushort_t* __restrict__ hf0B,
    ushort_t* __restrict__ hf1A, ushort_t* __restrict__ hf1B,
    const float* __restrict__ c0,     // [2][B][H]
    const float* __restrict__ W_hh0,  // [NG][H]
    const float* __restrict__ W_hh1,  // [NG][H]
    const float* __restrict__ W_ih1,  // [NG][H]
    const float* __restrict__ b1,     // [NG]
    float* __restrict__ hplain,       // [B][H] final layer-1 h
    int* __restrict__ flags) {        // NBLK*FLS ints, zeroed
    __shared__ __align__(16) ushort_t hfL0[16384];   // 32 KB expanded h0 A-frags
    __shared__ __align__(16) ushort_t hfL1[16384];   // 32 KB expanded h1 A-frags
    __shared__ float d0b[2][4 * 4 * 8 * 16];         // 2x8 KB layer0 partials
    __shared__ float d1b[2][4 * 4 * 8 * 16];         // 2x8 KB layer1 partials
    __shared__ short8 wlo[4 * 4 * 4 * 64];           // 64 KB W_ih1 lo B-frags
    const int tid = threadIdx.x, bid = blockIdx.x;
    const int g = bid >> 5, mB = bid & 31;
    const int j0 = mB * 16;
    const int bat0 = (g < 2) ? 7 * g : 14 + 6 * (g - 2);
    const int cnt  = (g < 2) ? 7 : 6;
    const int w = tid >> 6, L = tid & 63;

    // zero pad lanes (el&15 >= 8) of both frag buffers; stage never writes
    // them, MFMA reads them as 0.
    {
        ull_t* u0 = (ull_t*)hfL0;
        ull_t* u1 = (ull_t*)hfL1;
        for (int i = tid; i < 4096; i += 256)
            if ((((i >> 1) & 63) & 15) >= 8) { u0[i] = 0ULL; u1[i] = 0ULL; }
    }

    // ---- one-time W preload ----
    short8 Bhh0h[4][4], Bhh0l[4][4], Bhh1h[4][4], Bhh1l[4][4], Bih1h[4][4];
    {
        const int n = L & 15, oct = L >> 4;
#pragma unroll
        for (int q = 0; q < 4; ++q) {
            const size_t row = (size_t)(q * H_ + j0 + n) * H_;
#pragma unroll
            for (int kk = 0; kk < 4; ++kk) {
                int kbase = (w * 4 + kk) * 32 + oct * 8;
                // W_hh0
                {
                    float4 f0 = *(const float4*)(W_hh0 + row + kbase);
                    float4 f1 = *(const float4*)(W_hh0 + row + kbase + 4);
                    float xs[8] = {f0.x, f0.y, f0.z, f0.w, f1.x, f1.y, f1.z, f1.w};
                    union { ushort_t s[8]; short8 v; } uh, ul;
#pragma unroll
                    for (int e = 0; e < 8; ++e) {
                        ushort_t hi = bf16_rne(xs[e]);
                        uh.s[e] = hi; ul.s[e] = bf16_rne(xs[e] - bf16_tof(hi));
                    }
                    Bhh0h[q][kk] = uh.v; Bhh0l[q][kk] = ul.v;
                }
                // W_hh1
                {
                    float4 f0 = *(const float4*)(W_hh1 + row + kbase);
                    float4 f1 = *(const float4*)(W_hh1 + row + kbase + 4);
                    float xs[8] = {f0.x, f0.y, f0.z, f0.w, f1.x, f1.y, f1.z, f1.w};
                    union { ushort_t s[8]; short8 v; } uh, ul;
#pragma unroll
                    for (int e = 0; e < 8; ++e) {
                        ushort_t hi = bf16_rne(xs[e]);
                        uh.s[e] = hi; ul.s[e] = bf16_rne(xs[e] - bf16_tof(hi));
                    }
                    Bhh1h[q][kk] = uh.v; Bhh1l[q][kk] = ul.v;
                }
                // W_ih1: hi -> regs, lo -> LDS
                {
                    float4 f0 = *(const float4*)(W_ih1 + row + kbase);
                    float4 f1 = *(const float4*)(W_ih1 + row + kbase + 4);
                    float xs[8] = {f0.x, f0.y, f0.z, f0.w, f1.x, f1.y, f1.z, f1.w};
                    union { ushort_t s[8]; short8 v; } uh, ul;
#pragma unroll
                    for (int e = 0; e < 8; ++e) {
                        ushort_t hi = bf16_rne(xs[e]);
                        uh.s[e] = hi; ul.s[e] = bf16_rne(xs[e] - bf16_tof(hi));
                    }
                    Bih1h[q][kk] = uh.v;
                    wlo[((w * 4 + q) * 4 + kk) * 64 + L] = ul.v;
                }
            }
        }
    }

    // ---- gate-phase identities ----
    const int gm0 = tid >> 3, jlp0 = (tid & 7) * 2;
    const bool gok0 = (tid < 56) && (gm0 < cnt);
    const int gb0 = (bat0 + gm0 < B_) ? bat0 + gm0 : B_ - 1;
    float c0a = 0.f, c0b = 0.f;
    if (gok0) {
        c0a = c0[(size_t)gb0 * H_ + j0 + jlp0];
        c0b = c0[(size_t)gb0 * H_ + j0 + jlp0 + 1];
    }
    float2 xr[4];
    if (tid < 56) {
#pragma unroll
        for (int q = 0; q < 4; ++q)
            xr[q] = *(const float2*)(xg + (size_t)gb0 * NG_ + q * H_ + j0 + jlp0);
    }
    const int u1 = tid - 64;
    const int gm1 = u1 >> 3, jlp1 = (u1 & 7) * 2;
    const bool gok1 = (tid >= 64) && (tid < 120) && (gm1 < cnt);
    const int gb1 = (gok1 && bat0 + gm1 < B_) ? bat0 + gm1 : B_ - 1;
    float c1a = 0.f, c1b = 0.f;
    float2 b1r[4];
    if (gok1) {
        c1a = c0[(size_t)(B_ + gb1) * H_ + j0 + jlp1];
        c1b = c0[(size_t)(B_ + gb1) * H_ + j0 + jlp1 + 1];
#pragma unroll
        for (int q = 0; q < 4; ++q)
            b1r[q] = *(const float2*)(b1 + q * H_ + j0 + jlp1);
    }

    __syncthreads();   // wlo + pad-zero visible

    const short8* ap0 = (const short8*)hfL0;
    const short8* ap1 = (const short8*)hfL1;
    const f32x4 vzero = {0.f, 0.f, 0.f, 0.f};

    // this wave's flag pointer for the poll (8 producer blocks x 2 flags)
    const int* pollf = flags + (size_t)(g * 32 + 8 * w + (L & 7)) * FLS + ((L >> 3) & 1);

    for (int s = 0; s <= T_; ++s) {
        const ushort_t* r0 = (s & 1) ? hf0A : hf0B;   // h0(s-1)
        ushort_t*       w0 = (s & 1) ? hf0B : hf0A;
        const ushort_t* r1 = (s & 1) ? hf1B : hf1A;   // h1(s-2)
        ushort_t*       w1 = (s & 1) ? hf1A : hf1B;
        float* dw0 = d0b[s & 1];
        float* dw1 = d1b[s & 1];

        // ---- per-wave poll: wait for this wave's 8 producer blocks ----
        {
            for (;;) {
                int v = (L < 16)
                        ? __hip_atomic_load(pollf, __ATOMIC_RELAXED, __HIP_MEMORY_SCOPE_AGENT)
                        : s;
                if (__all(v >= s)) break;
                __builtin_amdgcn_s_sleep(2);
            }
        }

        // ---- per-wave stage: this wave's ks slice of both frag sets ----
        {
            const ull_t* s0 = (const ull_t*)(r0 + (size_t)g * 8192);
            const ull_t* s1 = (const ull_t*)(r1 + (size_t)g * 8192);
            ull_t* l0 = (ull_t*)hfL0;
            ull_t* l1 = (ull_t*)hfL1;
            ull_t v0[8], v1[8];
#pragma unroll
            for (int hl = 0; hl < 2; ++hl)
#pragma unroll
                for (int i = 0; i < 4; ++i) {
                    int u = hl * 1024 + w * 256 + i * 64 + L;
                    v0[hl * 4 + i] = __hip_atomic_load(s0 + u, __ATOMIC_RELAXED,
                                                       __HIP_MEMORY_SCOPE_AGENT);
                    v1[hl * 4 + i] = __hip_atomic_load(s1 + u, __ATOMIC_RELAXED,
                                                       __HIP_MEMORY_SCOPE_AGENT);
                }
#pragma unroll
            for (int hl = 0; hl < 2; ++hl)
#pragma unroll
                for (int i = 0; i < 4; ++i) {
                    int u = hl * 1024 + w * 256 + i * 64 + L;
                    int jjh = u & 1, cl = (u >> 1) & 31, ks = (u >> 6) & 15;
                    int el = (cl & 7) + 16 * (cl >> 3);
                    int di = ((hl * 16 + ks) * 64 + el) * 2 + jjh;
                    l0[di] = v0[hl * 4 + i];
                    l1[di] = v1[hl * 4 + i];
                }
        }
        // no barrier: each wave's MFMA reads only lines it staged itself.

        // ---- layer-0 MFMA (t0 = s) ----
        if (s < T_) {
            f32x4 acc[4];
#pragma unroll
            for (int q = 0; q < 4; ++q) acc[q] = vzero;
#pragma unroll
            for (int kk = 0; kk < 4; ++kk) {
                int ksp = w * 4 + kk;
                short8 Ahi = ap0[ksp * 64 + L];
                short8 Alo = ap0[1024 + ksp * 64 + L];
#pragma unroll
                for (int q = 0; q < 4; ++q) {
                    acc[q] = __builtin_amdgcn_mfma_f32_16x16x32_bf16(Ahi, Bhh0h[q][kk], acc[q], 0, 0, 0);
                    acc[q] = __builtin_amdgcn_mfma_f32_16x16x32_bf16(Alo, Bhh0h[q][kk], acc[q], 0, 0, 0);
                    acc[q] = __builtin_amdgcn_mfma_f32_16x16x32_bf16(Ahi, Bhh0l[q][kk], acc[q], 0, 0, 0);
                }
            }
#pragma unroll
            for (int q = 0; q < 4; ++q)
#pragma unroll
                for (int r = 0; r < 4; ++r) {
                    int m = (L >> 4) * 4 + r;
                    if (m < 8) dw0[((w * 4 + q) * 8 + m) * 16 + (L & 15)] = acc[q][r];
                }
        }
        // ---- layer-1 MFMA (t1 = s-1): W_ih1@h0(s-1) + W_hh1@h1(s-2) ----
        if (s >= 1) {
            f32x4 acc[4];
#pragma unroll
            for (int q = 0; q < 4; ++q) acc[q] = vzero;
#pragma unroll
            for (int kk = 0; kk < 4; ++kk) {
                int ksp = w * 4 + kk;
                short8 A0h = ap0[ksp * 64 + L];
                short8 A0l = ap0[1024 + ksp * 64 + L];
                short8 A1h = ap1[ksp * 64 + L];
                short8 A1l = ap1[1024 + ksp * 64 + L];
#pragma unroll
                for (int q = 0; q < 4; ++q) {
                    short8 Wl = wlo[((w * 4 + q) * 4 + kk) * 64 + L];
                    acc[q] = __builtin_amdgcn_mfma_f32_16x16x32_bf16(A0h, Bih1h[q][kk], acc[q], 0, 0, 0);
                    acc[q] = __builtin_amdgcn_mfma_f32_16x16x32_bf16(A0l, Bih1h[q][kk], acc[q], 0, 0, 0);
                    acc[q] = __builtin_amdgcn_mfma_f32_16x16x32_bf16(A0h, Wl, acc[q], 0, 0, 0);
                    acc[q] = __builtin_amdgcn_mfma_f32_16x16x32_bf16(A1h, Bhh1h[q][kk], acc[q], 0, 0, 0);
                    acc[q] = __builtin_amdgcn_mfma_f32_16x16x32_bf16(A1l, Bhh1h[q][kk], acc[q], 0, 0, 0);
                    acc[q] = __builtin_amdgcn_mfma_f32_16x16x32_bf16(A1h, Bhh1l[q][kk], acc[q], 0, 0, 0);
                }
            }
#pragma unroll
            for (int q = 0; q < 4; ++q)
#pragma unroll
                for (int r = 0; r < 4; ++r) {
                    int m = (L >> 4) * 4 + r;
                    if (m < 8) dw1[((w * 4 + q) * 8 + m) * 16 + (L & 15)] = acc[q][r];
                }
        }
        __syncthreads();   // B: d partials complete; drains stage loads

        // ---- layer-0 gate phase (wave 0) + flagA ----
        if (s < T_) {
            if (gok0) {
                float ga[4], gb[4];
#pragma unroll
                for (int q = 0; q < 4; ++q) {
                    float sx = 0.f, sy = 0.f;
#pragma unroll
                    for (int ww = 0; ww < 4; ++ww) {
                        const float2 p = *(const float2*)&dw0[((ww * 4 + q) * 8 + gm0) * 16 + jlp0];
                        sx += p.x; sy += p.y;
                    }
                    ga[q] = sx + xr[q].x;
                    gb[q] = sy + xr[q].y;
                }
                float cna = sigmf(ga[1]) * c0a + sigmf(ga[0]) * tanh_fast(ga[2]);
                float hna = sigmf(ga[3]) * tanh_fast(cna);
                float cnb = sigmf(gb[1]) * c0b + sigmf(gb[0]) * tanh_fast(gb[2]);
                float hnb = sigmf(gb[3]) * tanh_fast(cnb);
                c0a = cna; c0b = cnb;
                ushort_t hia = bf16_rne(hna), hib = bf16_rne(hnb);
                ushort_t loa = bf16_rne(hna - bf16_tof(hia));
                ushort_t lob = bf16_rne(hnb - bf16_tof(hib));
                int jA = j0 + jlp0;
                int cl = gm0 + 8 * ((jA >> 3) & 3);
                int ks = jA >> 5, jj = jA & 7;
                ushort_t* og = w0 + (size_t)g * 8192;
                unsigned hv = (unsigned)hia | ((unsigned)hib << 16);
                unsigned lv = (unsigned)loa | ((unsigned)lob << 16);
                __hip_atomic_store((unsigned*)(og + (ks * 256 + cl * 8 + jj)), hv,
                                   __ATOMIC_RELAXED, __HIP_MEMORY_SCOPE_AGENT);
                __hip_atomic_store((unsigned*)(og + (4096 + ks * 256 + cl * 8 + jj)), lv,
                                   __ATOMIC_RELAXED, __HIP_MEMORY_SCOPE_AGENT);
            }
        }
        if (tid == 0) {
            asm volatile("s_waitcnt vmcnt(0)" ::: "memory");
            __hip_atomic_store(flags + (size_t)bid * FLS + 0, s + 1,
                               __ATOMIC_RELAXED, __HIP_MEMORY_SCOPE_AGENT);
        }
        // prefetch next xg tile (after flagA so it doesn't delay the signal)
        if (tid < 56 && s + 1 < T_) {
#pragma unroll
            for (int q = 0; q < 4; ++q)
                xr[q] = *(const float2*)(xg + ((size_t)(s + 1) * B_ + gb0) * NG_ + q * H_ + j0 + jlp0);
        }

        // ---- layer-1 gate phase (wave 1) + flagB ----
        if (s >= 1 && gok1) {
            float ga[4], gb[4];
#pragma unroll
            for (int q = 0; q < 4; ++q) {
                float sx = 0.f, sy = 0.f;
#pragma unroll
                for (int ww = 0; ww < 4; ++ww) {
                    const float2 p = *(const float2*)&dw1[((ww * 4 + q) * 8 + gm1) * 16 + jlp1];
                    sx += p.x; sy += p.y;
                }
                ga[q] = sx + b1r[q].x;
                gb[q] = sy + b1r[q].y;
            }
            float cna = sigmf(ga[1]) * c1a + sigmf(ga[0]) * tanh_fast(ga[2]);
            float hna = sigmf(ga[3]) * tanh_fast(cna);
            float cnb = sigmf(gb[1]) * c1b + sigmf(gb[0]) * tanh_fast(gb[2]);
            float hnb = sigmf(gb[3]) * tanh_fast(cnb);
            c1a = cna; c1b = cnb;
            ushort_t hia = bf16_rne(hna), hib = bf16_rne(hnb);
            ushort_t loa = bf16_rne(hna - bf16_tof(hia));
            ushort_t lob = bf16_rne(hnb - bf16_tof(hib));
            int jA = j0 + jlp1;
            int cl = gm1 + 8 * ((jA >> 3) & 3);
            int ks = jA >> 5, jj = jA & 7;
            ushort_t* og = w1 + (size_t)g * 8192;
            unsigned hv = (unsigned)hia | ((unsigned)hib << 16);
            unsigned lv = (unsigned)loa | ((unsigned)lob << 16);
            __hip_atomic_store((unsigned*)(og + (ks * 256 + cl * 8 + jj)), hv,
                               __ATOMIC_RELAXED, __HIP_MEMORY_SCOPE_AGENT);
            __hip_atomic_store((unsigned*)(og + (4096 + ks * 256 + cl * 8 + jj)), lv,
                               __ATOMIC_RELAXED, __HIP_MEMORY_SCOPE_AGENT);
            if (s == T_) *(float2*)(hplain + (size_t)gb1 * H_ + jA) = make_float2(hna, hnb);
        }
        if (tid == 64) {
            asm volatile("s_waitcnt vmcnt(0)" ::: "memory");
            __hip_atomic_store(flags + (size_t)bid * FLS + 1, s + 1,
                               __ATOMIC_RELAXED, __HIP_MEMORY_SCOPE_AGENT);
        }
        // no barrier C: d buffers parity-swap; distance-2 reuse is protected
        // by the cross-block flag chain (see header comment).
    }
}

// ---------------------------------------------------------------------------
// head: hT layout [b][H]
// ---------------------------------------------------------------------------
__global__ __launch_bounds__(512) void head(
    const float* __restrict__ hT, const float* __restrict__ lin1_W,
    const float* __restrict__ lin1_b, const float* __restrict__ lin2_W,
    const float* __restrict__ lin2_b, float* __restrict__ out) {
    __shared__ float zs[B_][10];
    int tid = threadIdx.x;
    if (tid < B_ * 10) {
        int b = tid / 10, u = tid % 10;
        float acc = lin1_b[u];
        for (int j = 0; j < H_; j += 4) {
            float4 hv = *(const float4*)&hT[(size_t)b * H_ + j];
            float4 wv = *(const float4*)&lin1_W[(size_t)u * H_ + j];
            acc = fmaf(hv.x, wv.x, acc);
            acc = fmaf(hv.y, wv.y, acc);
            acc = fmaf(hv.z, wv.z, acc);
            acc = fmaf(hv.w, wv.w, acc);
        }
        zs[b][u] = tanh_fast(acc);
    }
    __syncthreads();
    if (tid < B_ * 2) {
        int b = tid >> 1, o = tid & 1;
        float acc = lin2_b[o];
#pragma unroll
        for (int u = 0; u < 10; ++u)
            acc = fmaf(zs[b][u], lin2_W[o * 10 + u], acc);
        out[b * 2 + o] = acc;
    }
}

// ---------------------------------------------------------------------------
extern "C" void kernel_launch(void* const* d_in, const int* in_sizes, int n_in,
                              void* d_out, int out_size, void* d_ws, size_t ws_size,
                              hipStream_t stream) {
    const float* input  = (const float*)d_in[0];
    const float* pca_W  = (const float*)d_in[1];
    const float* pca_b  = (const float*)d_in[2];
    const float* W_ih0  = (const float*)d_in[3];
    const float* W_hh0  = (const float*)d_in[4];
    const float* b0     = (const float*)d_in[5];
    const float* W_ih1  = (const float*)d_in[6];
    const float* W_hh1  = (const float*)d_in[7];
    const float* b1     = (const float*)d_in[8];
    const float* h0     = (const float*)d_in[9];
    const float* c0     = (const float*)d_in[10];
    const float* lin1_W = (const float*)d_in[11];
    const float* lin1_b = (const float*)d_in[12];
    const float* lin2_W = (const float*)d_in[13];
    const float* lin2_b = (const float*)d_in[14];
    float* out = (float*)d_out;

    float* ws = (float*)d_ws;
    size_t off = 0;
    float* xg     = ws + off; off += (size_t)B_ * T_ * NG_;  // [T][B][NG]
    float* xbuf   = ws + off; off += (size_t)B_ * T_ * H_;
    float* hplain = ws + off; off += B_ * H_;
    ushort_t* hf0A = (ushort_t*)(ws + off); off += 32768;    // 8 x 8192 ushorts
    ushort_t* hf0B = (ushort_t*)(ws + off); off += 32768;
    ushort_t* hf1A = (ushort_t*)(ws + off); off += 32768;
    ushort_t* hf1B = (ushort_t*)(ws + off); off += 32768;
    int* flg = (int*)(ws + off); off += NBLK * FLS;

    const int M = B_ * T_;  // 25600

    // flags must start at 0 (ws re-poisoned 0xAA before every timed launch)
    hipMemsetAsync(flg, 0, NBLK * FLS * sizeof(int), stream);

    // initial states -> frag buffers (read at s=0 / s=1 respectively)
    init_hfrag<<<8, 256, 0, stream>>>(h0, hf0B);
    init_hfrag<<<8, 256, 0, stream>>>(h0 + B_ * H_, hf1B);

    // 1. pca: xbuf = input @ pca_W^T + pca_b   (row-major [B*T][H])
    {
        dim3 g(H_ / 128, M / 128);
        gemm_bias_mfma<<<g, 256, 0, stream>>>(input, pca_W, pca_b, xbuf, M, H_, I_, 0);
    }
    // 2. xg0 = xbuf @ W_ih0^T + b0, stored [T][B][NG]
    {
        dim3 g(NG_ / 128, M / 128);
        gemm_bias_mfma<<<g, 256, 0, stream>>>(xbuf, W_ih0, b0, xg, M, NG_, H_, 1);
    }
    // 3. fused 2-layer pipelined scan (1 barrier/step, wlo in LDS as R2)
    lstm_fused<<<NBLK, 256, 0, stream>>>(xg, hf0A, hf0B, hf1A, hf1B, c0,
                                         W_hh0, W_hh1, W_ih1, b1, hplain, flg);
    // 4. head
    head<<<1, 512, 0, stream>>>(hplain, lin1_W, lin1_b, lin2_W, lin2_b, out);
}